// Round 14
// baseline (263.404 us; speedup 1.0000x reference)
//
#include <hip/hip_runtime.h>
#include <hip/hip_bf16.h>

#define D_MODEL 1024
#define NHEAD   16
#define HEAD_DIM 64
#define BATCH   2
#define SEQ     2048
#define NTOK    (BATCH*SEQ)   // 4096

// log2(10000)/64
#define FREQ_LOG2 0.20762050593046015f

typedef short  bfrag __attribute__((ext_vector_type(8)));  // 8 bf16 = 4 VGPR
typedef float  ffrag __attribute__((ext_vector_type(4)));  // C/D frag

__device__ inline ushort f2bf(float x) {
    __hip_bfloat16 h = __float2bfloat16(x);
    return __builtin_bit_cast(ushort, h);
}
__device__ inline float bf2f(ushort u) {
    return __builtin_bit_cast(float, (uint)u << 16);
}
__device__ inline void split_bf(float x, ushort& hi, ushort& lo) {
    __hip_bfloat16 h = __float2bfloat16(x);
    hi = __builtin_bit_cast(ushort, h);
    lo = f2bf(x - __bfloat162float(h));
}

// async global->LDS DMA, 16B per lane (lds dest = uniform base + lane*16)
__device__ inline void gload16(const ushort* g, ushort* l) {
    __builtin_amdgcn_global_load_lds(
        (const __attribute__((address_space(1))) void*)g,
        (__attribute__((address_space(3))) void*)l, 16, 0, 0);
}

// barrier that drains ONLY LDS ops (lgkmcnt) — leaves the wave-private
// global register prefetch loads (vmcnt) in flight across the barrier (T4).
__device__ inline void barrier_lds_only() {
    asm volatile("s_waitcnt lgkmcnt(0)\n\ts_barrier" ::: "memory");
}

// gemm prologue barrier: drain al(k=0)+stage(buf0), keep stage(buf1) [2 ops].
__device__ inline void barrier_vm2() {
    asm volatile("s_waitcnt vmcnt(2) lgkmcnt(0)\n\ts_barrier" ::: "memory");
}

// gemm steady-state barrier (T4 counted): per iter each thread issues
// 2 stage-DMAs (tile i+2) then 2 al-loads (tile i+1); keeping the 4 NEWEST
// in flight drains exactly stage(i+1) — the buffer the next iteration reads.
__device__ inline void barrier_vm4() {
    asm volatile("s_waitcnt vmcnt(4) lgkmcnt(0)\n\ts_barrier" ::: "memory");
}

// ---------------------------------------------------------------------------
// Fused pre-pass:
//   blocks [0,4096):     data -> Ahi/Alo bf16 hi/lo split
//   blocks [4096,8192):  mask fp32 -> bf16  + per-block nonzero flag MZnz
//   blocks [8192,8960):  W[k][n] -> WT[n][k] bf16 (LDS transpose)
//   blocks [8960,9472):  RoPE cos/sin table (fp32; bit-identical expressions)
// ---------------------------------------------------------------------------
__global__ __launch_bounds__(256)
void prep(const float* __restrict__ data, ushort* __restrict__ Ahi,
          ushort* __restrict__ Alo,
          const float* __restrict__ mask, ushort* __restrict__ Mbf,
          int* __restrict__ MZnz,
          const float* __restrict__ Wq, const float* __restrict__ Wk,
          const float* __restrict__ Wv, ushort* __restrict__ WThi,
          const float* __restrict__ temporal, float* __restrict__ cst)
{
    __shared__ float T[64][65];
    __shared__ int bnz;
    const int bid = blockIdx.x, t = threadIdx.x;

    if (bid < 4096) {                       // split_data
        const int i4 = (bid * 256 + t) * 4;
        const float4 v = *(const float4*)(data + i4);
        ushort4 h, l;
        split_bf(v.x, h.x, l.x); split_bf(v.y, h.y, l.y);
        split_bf(v.z, h.z, l.z); split_bf(v.w, h.w, l.w);
        *(ushort4*)(Ahi + i4) = h;
        *(ushort4*)(Alo + i4) = l;
        return;
    }
    if (bid < 8192) {                       // mask -> bf16 + nonzero flag
        const int mi = bid - 4096;
        const int i4 = (mi * 256 + t) * 4;
        const float4 v = *(const float4*)(mask + i4);
        ushort4 h;
        h.x = f2bf(v.x); h.y = f2bf(v.y); h.z = f2bf(v.z); h.w = f2bf(v.w);
        *(ushort4*)(Mbf + i4) = h;
        const int nz = (v.x != 0.f) || (v.y != 0.f) || (v.z != 0.f) || (v.w != 0.f);
        if (t == 0) bnz = 0;
        __syncthreads();
        if (nz) atomicOr(&bnz, 1);
        __syncthreads();
        if (t == 0) MZnz[mi] = bnz;
        return;
    }
    if (bid < 8960) {                       // W transpose
        const int id  = bid - 8192;         // 0..767
        const int z   = id >> 8;
        const int rem = id & 255;
        const int k0  = (rem & 15) * 64, n0 = (rem >> 4) * 64;
        const float* W = (z == 0) ? Wq : (z == 1) ? Wk : Wv;
        ushort* thi = WThi + (size_t)z * D_MODEL * D_MODEL;

        #pragma unroll
        for (int i = 0; i < 4; i++) {
            const int f = i * 256 + t, r = f >> 4, c = (f & 15) * 4;
            const float4 v = *(const float4*)(W + (size_t)(k0 + r) * D_MODEL + n0 + c);
            T[r][c] = v.x; T[r][c + 1] = v.y; T[r][c + 2] = v.z; T[r][c + 3] = v.w;
        }
        __syncthreads();
        #pragma unroll
        for (int i = 0; i < 4; i++) {
            const int f = i * 256 + t, nr = f >> 4, kc = (f & 15) * 4;
            ushort4 h;
            h.x = f2bf(T[kc + 0][nr]);
            h.y = f2bf(T[kc + 1][nr]);
            h.z = f2bf(T[kc + 2][nr]);
            h.w = f2bf(T[kc + 3][nr]);
            const size_t o = (size_t)(n0 + nr) * D_MODEL + k0 + kc;
            *(ushort4*)(thi + o) = h;
        }
        return;
    }
    // RoPE table: cst[m*64 + d] = cos, [.. + d + 1] = sin  (d even)
    const int id3 = bid - 8960;             // 0..511
    const int m   = id3 * 8 + (t >> 5);     // 0..4095
    const int j   = t & 31;                 // pair index, d = 2j
    const float tv = temporal[m];
    const float fr = exp2f(-(float)(2 * j) * FREQ_LOG2);
    float s, c;
    __sincosf(tv * fr, &s, &c);
    *(float2*)(cst + (size_t)m * 64 + 2 * j) = make_float2(c, s);
}

// ---------------------------------------------------------------------------
// Kernel 3: bf16x2 GEMM 128x128xBK32 + bias + RoPE epilogue.
// R14: 512-thread blocks (8 waves, wave tile 32x64, acc[2][4]) — TLP
// 12 -> 24 waves/CU at unchanged tile/swizzle/triple-buffer/counted-vmcnt
// structure.  Per thread per iter: 2 stage-DMAs + 2 al-loads -> vmcnt(4)
// barrier.  Same math, same accumulation order -> bit-identical output.
// ---------------------------------------------------------------------------
#define BK 32   // K-step; one LDS row = 32 bf16 = 64B = 4 chunks of 16B

union GemmSM {
    ushort st[3][2][128 * BK];   // [buf][ahi,bhi][row*BK+col]  = 48 KB
    float  c[64 * 132];          // epilogue scratch (33.8 KB)
};

__global__ __launch_bounds__(512, 6)
void gemm_qkv(const ushort* __restrict__ Ahi, const ushort* __restrict__ Alo,
              const ushort* __restrict__ WThi,
              const float* __restrict__ bq, const float* __restrict__ bk,
              const float* __restrict__ bv, const float* __restrict__ cst,
              const int* __restrict__ MZnz, int* __restrict__ Flag,
              ushort* __restrict__ Qhi, ushort* __restrict__ Qlo,
              ushort* __restrict__ Khi,
              ushort* __restrict__ VT)
{
    __shared__ GemmSM sm;
    __shared__ int flg;
    // XCD swizzle: bidl%8 = XCD slot; XCD x gets m-slabs 4x..4x+3 for all n,z
    const int bidl = blockIdx.x;                 // 0..767
    const int xcd  = bidl & 7, kk = bidl >> 3;   // kk 0..95
    const int m0   = (xcd * 4 + (kk & 3)) * 128;
    const int nz   = kk >> 2;                    // 0..23
    const int n0   = (nz & 7) * 128;
    const int z    = nz >> 3;

    const int t = threadIdx.x;

    if (bidl == 0) {      // mask-zero flag reduce (16 KB read, one block)
        if (t == 0) flg = 0;
        __syncthreads();
        if (t < 256) {
            int acc = 0;
            const int4* z4 = (const int4*)MZnz;
            #pragma unroll
            for (int i = 0; i < 4; i++) {
                const int4 v = z4[t * 4 + i];
                acc |= v.x | v.y | v.z | v.w;
            }
            if (acc) atomicOr(&flg, 1);
        }
        __syncthreads();
        if (t == 0) Flag[0] = flg;
    }

    const float* bias = (z == 0) ? bq : (z == 1) ? bk : bv;
    const ushort* Bh = WThi + (size_t)z * D_MODEL * D_MODEL;

    const int w = t >> 6, lane = t & 63;
    const int lane15 = lane & 15, quad = lane >> 4;
    const int wm = (w & 3) * 32;     // wave's 32-row m-slot
    const int wn = (w >> 2) * 64;    // wave's 64-col n-slot

    ffrag acc[2][4];
    #pragma unroll
    for (int i = 0; i < 2; i++)
        #pragma unroll
        for (int j = 0; j < 4; j++) acc[i][j] = (ffrag){0.f, 0.f, 0.f, 0.f};

    // DMA staging (Ahi + B): thread t covers row t>>2, physical chunk t&3;
    // fetches logical chunk (t&3)^((t>>3)&3)  [= (row>>1)&3 key].
    // Per wave: rows w*16..w*16+15 — LDS dest = uniform base + lane*16.
    const int sr = t >> 2;                                  // staged row
    const int lc = (((t & 3) ^ ((t >> 3) & 3))) * 8;        // swizzled col
    const int wbase = (t >> 6) * 16 * BK;                   // wave-uniform

    auto stage = [&](int bsel, int k0) {
        const ushort* ga = Ahi + (size_t)(m0 + sr) * D_MODEL + k0 + lc;
        const ushort* gb = Bh  + (size_t)(n0 + sr) * D_MODEL + k0 + lc;
        gload16(ga, &sm.st[bsel][0][wbase]);
        gload16(gb, &sm.st[bsel][1][wbase]);
    };

    // Alo fragment prefetch (registers, direct from global) for k=0
    const int quad8 = quad * 8;
    bfrag alp0, alp1;
    alp0 = *(const bfrag*)(Alo + (size_t)(m0 + wm +  0 + lane15) * D_MODEL + quad8);
    alp1 = *(const bfrag*)(Alo + (size_t)(m0 + wm + 16 + lane15) * D_MODEL + quad8);

    stage(0, 0);
    stage(1, BK);
    barrier_vm2();   // drain al(k=0)+stage(buf0); keep stage(buf1) [2 ops]

    // read-side swizzle: logical chunk 'quad' at row (16-aligned + lane15)
    const int rdsw = (quad ^ ((lane15 >> 1) & 3)) * 8;

    int cur = 0;
    for (int i = 0; i < 32; i++) {
        const int k0 = i * BK;
        // 1) stage tile i+2 into buf (cur+2)%3 (tail: harmless over-read)
        const int st2 = (cur >= 1) ? cur - 1 : 2;
        stage(st2, k0 + 2 * BK);

        // 2) consume this tile's al regs; issue next tile's al prefetch
        bfrag al0 = alp0, al1 = alp1;
        {
            const int kn = k0 + BK;
            alp0 = *(const bfrag*)(Alo + (size_t)(m0 + wm +  0 + lane15) * D_MODEL + kn + quad8);
            alp1 = *(const bfrag*)(Alo + (size_t)(m0 + wm + 16 + lane15) * D_MODEL + kn + quad8);
        }

        bfrag ah0 = *(const bfrag*)&sm.st[cur][0][(wm +  0 + lane15) * BK + rdsw];
        bfrag ah1 = *(const bfrag*)&sm.st[cur][0][(wm + 16 + lane15) * BK + rdsw];

        #pragma unroll
        for (int nt = 0; nt < 4; nt++) {
            const bfrag bh = *(const bfrag*)&sm.st[cur][1][(wn + nt * 16 + lane15) * BK + rdsw];
            {
                ffrag a = acc[0][nt];
                a = __builtin_amdgcn_mfma_f32_16x16x32_bf16(ah0, bh, a, 0, 0, 0);
                a = __builtin_amdgcn_mfma_f32_16x16x32_bf16(al0, bh, a, 0, 0, 0);
                acc[0][nt] = a;
            }
            {
                ffrag a = acc[1][nt];
                a = __builtin_amdgcn_mfma_f32_16x16x32_bf16(ah1, bh, a, 0, 0, 0);
                a = __builtin_amdgcn_mfma_f32_16x16x32_bf16(al1, bh, a, 0, 0, 0);
                acc[1][nt] = a;
            }
        }
        // 3) counted barrier: drain stage(i+1); keep stage(i+2)+al(i+1)
        barrier_vm4();
        cur = (cur == 2) ? 0 : cur + 1;
    }

    float bn[4];
    #pragma unroll
    for (int nt = 0; nt < 4; nt++) bn[nt] = bias[n0 + wn + nt * 16 + lane15];

    const int CST = (z == 2) ? 129 : 132;
    const int wlow = w & 1;   // row sub-slot within the phase

    #pragma unroll
    for (int p = 0; p < 2; p++) {
        if (p) __syncthreads();
        if (((w & 3) >> 1) == p) {
            #pragma unroll
            for (int mt = 0; mt < 2; mt++)
                #pragma unroll
                for (int nt = 0; nt < 4; nt++)
                    #pragma unroll
                    for (int rr = 0; rr < 4; rr++)
                        sm.c[(wlow * 32 + mt * 16 + quad * 4 + rr) * CST +
                             wn + nt * 16 + lane15] = acc[mt][nt][rr] + bn[nt];
        }
        __syncthreads();

        if (z < 2) {
            ushort* ohi = (z == 0) ? Qhi : Khi;
            const float sc = (z == 0) ? 0.125f : 1.0f;
            #pragma unroll
            for (int i = 0; i < 4; i++) {
                const int f = i * 512 + t, r = f >> 5, c4 = (f & 31) * 4;
                float4 v = *(float4*)&sm.c[r * 132 + c4];
                const int m = m0 + p * 64 + r;
                const float4 cs4 = *(const float4*)(cst + (size_t)m * 64 + (c4 & 63));
                const float c0 = cs4.x, s0 = cs4.y, c1v = cs4.z, s1 = cs4.w;
                const float y0 = (v.x * c0 - v.y * s0) * sc;
                const float y1 = (v.y * c0 + v.x * s0) * sc;
                const float y2 = (v.z * c1v - v.w * s1) * sc;
                const float y3 = (v.w * c1v + v.z * s1) * sc;
                ushort4 h, l;
                split_bf(y0, h.x, l.x); split_bf(y1, h.y, l.y);
                split_bf(y2, h.z, l.z); split_bf(y3, h.w, l.w);
                const size_t o = (size_t)m * D_MODEL + n0 + c4;
                *(ushort4*)(ohi + o) = h;
                if (z == 0) *(ushort4*)(Qlo + o) = l;   // K needs no lo
            }
        } else {
            const int bb = m0 >> 11;
            #pragma unroll
            for (int i = 0; i < 2; i++) {
                const int cid = i * 512 + t, col = cid >> 3, tg = (cid & 7) * 8;
                ushort u8[8];
                #pragma unroll
                for (int j = 0; j < 8; j++) u8[j] = f2bf(sm.c[(tg + j) * 129 + col]);
                const int ncol = n0 + col, hh = ncol >> 6, d = ncol & 63;
                const size_t dst = ((size_t)(bb * NHEAD + hh) * HEAD_DIM + d) * SEQ +
                                   (m0 & (SEQ - 1)) + p * 64 + tg;
                *(int4*)(VT + dst) = *(int4*)u8;
            }
        }
    }
}

// ---------------------------------------------------------------------------
// Kernel 4: MFMA flash attention — unchanged from R13 (KVBLK=128 two-half
// tiles, dbuf K/V, single LDS-only barrier, XOR swizzles, setprio, mask-zero
// fast path, l via ones-MFMA, saddr-split prefetch).
// ---------------------------------------------------------------------------
__global__ __launch_bounds__(256, 2)
void attn_mfma(const ushort* __restrict__ Qhi, const ushort* __restrict__ Qlo,
               const ushort* __restrict__ Khi,
               const ushort* __restrict__ VT,  const ushort* __restrict__ maskbf,
               const int* __restrict__ Flag,
               float* __restrict__ out)
{
    __shared__ ushort lsK[2][128 * 64], lsV[2][64 * 128], lsP[128 * 64];

    const int bid  = blockIdx.x;
    const int bh   = (bid & 7) * 4 + (bid >> 7);
    const int qb   = (bid >> 3) & 15;
    const int b    = bh >> 4, h = bh & 15;
    const int q0   = qb * 128;

    const int t = threadIdx.x, w = t >> 6, lane = t & 63;
    const int lane15 = lane & 15, quad = lane >> 4;
    const size_t tok0 = (size_t)b * SEQ;

    const int mz = Flag[0];            // 0 => mask is entirely zero

    // loop-invariant Q fragments (A-layout), 2 subtiles per wave
    bfrag qh[2][2], ql[2][2];
    #pragma unroll
    for (int su = 0; su < 2; su++) {
        const size_t qrow = (tok0 + q0 + w * 32 + su * 16 + lane15) * D_MODEL +
                            h * HEAD_DIM;
        #pragma unroll
        for (int ks = 0; ks < 2; ks++) {
            qh[su][ks] = *(const bfrag*)(Qhi + qrow + ks * 32 + quad * 8);
            ql[su][ks] = *(const bfrag*)(Qlo + qrow + ks * 32 + quad * 8);
        }
    }

    // all-ones bf16 fragment (B-operand for the l-MFMA)
    const short one_bf = (short)0x3F80;
    const bfrag ones = {one_bf, one_bf, one_bf, one_bf,
                        one_bf, one_bf, one_bf, one_bf};

    ffrag of[2][4], of_l[2];
    #pragma unroll
    for (int su = 0; su < 2; su++) {
        of_l[su] = (ffrag){0.f, 0.f, 0.f, 0.f};
        #pragma unroll
        for (int nt = 0; nt < 4; nt++)
            of[su][nt] = (ffrag){0.f, 0.f, 0.f, 0.f};
    }

    // K staging: thread covers rows rK+{0,32,64,96}, 16B chunk at cK.
    const int rK  = t >> 3, cK = (t & 7) * 8;
    const int swK = ((t & 7) ^ (rK & 7)) * 8;          // 8-chunk XOR (row&7)
    // V staging: thread covers row rV (d), 4 chunks lch=(t&3)+4*ch of 16.
    const int rV   = t >> 2;
    const int keyV = ((rV & 3) << 2) | ((rV >> 2) & 3);
    const ushort* Kh0 = Khi + tok0 * D_MODEL + h * HEAD_DIM;
    const ushort* Vt0 = VT + (size_t)(b * NHEAD + h) * HEAD_DIM * SEQ;

    // loop-invariant per-lane offsets (saddr-split)
    const size_t kof0 = (size_t)(rK +  0) * D_MODEL + cK;
    const size_t kof1 = (size_t)(rK + 32) * D_MODEL + cK;
    const size_t kof2 = (size_t)(rK + 64) * D_MODEL + cK;
    const size_t kof3 = (size_t)(rK + 96) * D_MODEL + cK;
    const size_t vof  = (size_t)rV * SEQ + (t & 3) * 8;

    // tile 0 (k 0..127) into regs
    int4 pk0 = *(const int4*)(Kh0 + kof0);
    int4 pk1 = *(const int4*)(Kh0 + kof1);
    int4 pk2 = *(const int4*)(Kh0 + kof2);
    int4 pk3 = *(const int4*)(Kh0 + kof3);
    int4 pv0 = *(const int4*)(Vt0 + vof +  0);
    int4 pv1 = *(const int4*)(Vt0 + vof + 32);
    int4 pv2 = *(const int4*)(Vt0 + vof + 64);
    int4 pv3 = *(const int4*)(Vt0 + vof + 96);

    // tile 0 regs -> buf0
    *(int4*)&lsK[0][(rK +  0) * 64 + swK] = pk0;
    *(int4*)&lsK[0][(rK + 32) * 64 + swK] = pk1;
    *(int4*)&lsK[0][(rK + 64) * 64 + swK] = pk2;
    *(int4*)&lsK[0][(rK + 96) * 64 + swK] = pk3;
    *(int4*)&lsV[0][rV * 128 + (((t & 3) +  0) ^ keyV) * 8] = pv0;
    *(int4*)&lsV[0][rV * 128 + (((t & 3) +  4) ^ keyV) * 8] = pv1;
    *(int4*)&lsV[0][rV * 128 + (((t & 3) +  8) ^ keyV) * 8] = pv2;
    *(int4*)&lsV[0][rV * 128 + (((t & 3) + 12) ^ keyV) * 8] = pv3;

    // tile 1 (k 128..255) into regs
    pk0 = *(const int4*)(Kh0 + 128 * D_MODEL + kof0);
    pk1 = *(const int4*)(Kh0 + 128 * D_MODEL + kof1);
    pk2 = *(const int4*)(Kh0 + 128 * D_MODEL + kof2);
    pk3 = *(const int4*)(Kh0 + 128 * D_MODEL + kof3);
    pv0 = *(const int4*)(Vt0 + 128 + vof +  0);
    pv1 = *(const int4*)(Vt0 + 128 + vof + 32);
    pv2 = *(const int4*)(Vt0 + 128 + vof + 64);
    pv3 = *(const int4*)(Vt0 + 128 + vof + 96);
    barrier_lds_only();

    const ushort* mrow0 = maskbf + (size_t)(q0 + w * 32 + quad * 4) * SEQ;
    const ushort* mrow1 = maskbf + (size_t)(q0 + w * 32 + 16 + quad * 4) * SEQ;

    const int krd  = lane15 & 7;                                  // K rows
    const int keyr = (((lane15 >> 2) & 3) << 1) | (lane15 & 1);   // P rows
    const int keyVr = ((lane15 & 3) << 2) | ((lane15 >> 2) & 3);  // V rows

    int cur = 0;
    for (int kt = 0; kt < SEQ; kt += 128) {
        // 1) regs (tile kt+128) -> buf cur^1
        if (kt + 128 < SEQ) {
            *(int4*)&lsK[cur ^ 1][(rK +  0) * 64 + swK] = pk0;
            *(int4*)&lsK[cur ^ 1][(rK + 32) * 64 + swK] = pk1;
            *(int4*)&lsK[cur ^ 1][(rK + 64) * 64 + swK] = pk2;
            *(int4*)&lsK[cur ^ 1][(rK + 96) * 64 + swK] = pk3;
            *(int4*)&lsV[cur ^ 1][rV * 128 + (((t & 3) +  0) ^ keyV) * 8] = pv0;
            *(int4*)&lsV[cur ^ 1][rV * 128 + (((t & 3) +  4) ^ keyV) * 8] = pv1;
            *(int4*)&lsV[cur ^ 1][rV * 128 + (((t & 3) +  8) ^ keyV) * 8] = pv2;
            *(int4*)&lsV[cur ^ 1][rV * 128 + (((t & 3) + 12) ^ keyV) * 8] = pv3;
        }

        // 2) global prefetch tile kt+256 (wrap -> harmless reload of tile 0)
        const int ktn = (kt + 256 < SEQ) ? kt + 256 : 0;
        const ushort* KhT = Kh0 + (size_t)ktn * D_MODEL;   // wave-uniform base
        const ushort* VtT = Vt0 + ktn;
        pk0 = *(const int4*)(KhT + kof0);
        pk1 = *(const int4*)(KhT + kof1);
        pk2 = *(const int4*)(KhT + kof2);
        pk3 = *(const int4*)(KhT + kof3);
        pv0 = *(const int4*)(VtT + vof +  0);
        pv1 = *(const int4*)(VtT + vof + 32);
        pv2 = *(const int4*)(VtT + vof + 64);
        pv3 = *(const int4*)(VtT + vof + 96);

        // 3) two 64-halves; no barrier between (P reuse safe: DS in-order)
        #pragma unroll
        for (int half = 0; half < 2; half++) {
            const int kb = kt + half * 64;

            // mask (bf16) — only when mask has nonzeros
            float mv0[4][4], mv1[4][4];
            if (mz) {
                #pragma unroll
                for (int nt = 0; nt < 4; nt++)
                    #pragma unroll
                    for (int rr = 0; rr < 4; rr++) {
                        mv0[nt][rr] = bf2f(mrow0[(size_t)rr * SEQ + kb + nt * 16 + lane15]);
                        mv1[nt][rr] = bf2f(mrow1[(size_t)rr * SEQ + kb + nt * 16 + lane15]);
                    }
            }

            // S = (Q/8) K^T for both subtiles; kf read ONCE per nt
            ffrag s0[4], s1[4];
            __builtin_amdgcn_s_setprio(1);
            #pragma unroll
            for (int nt = 0; nt < 4; nt++) {
                const int krow = half * 64 + nt * 16 + lane15;
                const bfrag kf0 = *(const bfrag*)&lsK[cur][krow * 64 + ((0 + quad) ^ krd) * 8];
                const bfrag kf1 = *(const bfrag*)&lsK[cur][krow * 64 + ((4 + quad) ^ krd) * 8];
                ffrag a0 = (ffrag){0.f, 0.f, 0.f, 0.f};
                ffrag a1 = (ffrag){0.f, 0.f, 0.f, 0.f};
                a0 = __builtin_amdgcn_mfma_f32_16x16x32_bf16(qh[0][0], kf0, a0, 0, 0, 0);
                a0 = __builtin_amdgcn_mfma_f32_16x16x32_bf16(ql[0][0], kf0, a0, 0, 0, 0);
                a0 = __builtin_amdgcn_mfma_f32_16x16x32_bf16(qh[0][1], kf1, a0, 0, 0, 0);
                a0 = __builtin_amdgcn_mfma_f32_16x16x32_bf16(ql[0][1], kf1, a0, 0, 0, 0);
                a1 = __builtin_amdgcn_mfma_f32_16x16x32_bf16(qh[1][0], kf0, a1, 0, 0, 0);
                a1 = __builtin_amdgcn_mfma_f32_16x16x32_bf16(ql[1][0], kf0, a1, 0, 0, 0);
                a1 = __builtin_amdgcn_mfma_f32_16x16x32_bf16(qh[1][1], kf1, a1, 0, 0, 0);
                a1 = __builtin_amdgcn_mfma_f32_16x16x32_bf16(ql[1][1], kf1, a1, 0, 0, 0);
                s0[nt] = a0;
                s1[nt] = a1;
            }
            __builtin_amdgcn_s_setprio(0);

            // streaming softmax: exp, P^T -> swizzled LDS (l via ones-MFMA)
            #pragma unroll
            for (int nt = 0; nt < 4; nt++)
                #pragma unroll
                for (int rr = 0; rr < 4; rr++) {
                    const int pchk = (2 * nt + (lane15 >> 3)) ^ ((quad << 1) | (rr & 1));
                    float x0 = s0[nt][rr];
                    float x1 = s1[nt][rr];
                    if (mz) { x0 += mv0[nt][rr]; x1 += mv1[nt][rr]; }
                    const float e0 = __expf(x0);
                    lsP[(w * 32 + quad * 4 + rr) * 64 + pchk * 8 + (lane15 & 7)] = f2bf(e0);
                    const float e1 = __expf(x1);
                    lsP[(w * 32 + 16 + quad * 4 + rr) * 64 + pchk * 8 + (lane15 & 7)] = f2bf(e1);
                }

            // O += P V  and  l += P·ones  (P rows wave-private: no barrier)
            __builtin_amdgcn_s_setprio(1);
            #pragma unroll
            for (int ksl = 0; ksl < 2; ksl++) {
                const bfrag pf0 = *(const bfrag*)&lsP[(w * 32 + lane15) * 64 +
                                                      ((ksl * 4 + quad) ^ keyr) * 8];
                const bfrag pf1 = *(const bfrag*)&lsP[(w * 32 + 16 + lane15) * 64 +
                                                      ((ksl * 4 + quad) ^ keyr) * 8];
                const int lkc = half * 8 + ksl * 4 + quad;   // logical V k-chunk
                #pragma unroll
                for (int nt = 0; nt < 4; nt++) {
                    const bfrag vf = *(const bfrag*)&lsV[cur][(nt * 16 + lane15) * 128 +
                                                              (lkc ^ keyVr) * 8];
                    of[0][nt] = __builtin_amdgcn_mfma_f32_16x16x32_bf16(pf0, vf, of[0][nt], 0, 0, 0);
                    of[1][nt] = __builtin_amdgcn_mfma_f32_16x16x32_bf16(pf1, vf, of[1][nt], 0, 0, 0);
                }
                of_l[0] = __builtin_amdgcn_mfma_f32_16x16x32_bf16(pf0, ones, of_l[0], 0, 0, 0);
                of_l[1] = __builtin_amdgcn_mfma_f32_16x16x32_bf16(pf1, ones, of_l[1], 0, 0, 0);
            }
            __builtin_amdgcn_s_setprio(0);
        }

        // 4) single barrier per 128-tile — LDS-only drain (vmcnt counted)
        barrier_lds_only();
        cur ^= 1;
    }

    #pragma unroll
    for (int su = 0; su < 2; su++) {
        float inv[4];
        #pragma unroll
        for (int rr = 0; rr < 4; rr++)
            inv[rr] = 1.0f / of_l[su][rr];    // D columns all equal: full sum
        #pragma unroll
        for (int nt = 0; nt < 4; nt++)
            #pragma unroll
            for (int rr = 0; rr < 4; rr++)
                out[(tok0 + q0 + w * 32 + su * 16 + quad * 4 + rr) * D_MODEL +
                    h * HEAD_DIM + nt * 16 + lane15] = of[su][nt][rr] * inv[rr];
    }
}

// ---------------------------------------------------------------------------
extern "C" void kernel_launch(void* const* d_in, const int* in_sizes, int n_in,
                              void* d_out, int out_size, void* d_ws, size_t ws_size,
                              hipStream_t stream)
{
    const float* data     = (const float*)d_in[0];
    const float* temporal = (const float*)d_in[1];
    const float* mask     = (const float*)d_in[2];
    const float* Wq = (const float*)d_in[3];
    const float* bq = (const float*)d_in[4];
    const float* Wk = (const float*)d_in[5];
    const float* bk = (const float*)d_in[6];
    const float* Wv = (const float*)d_in[7];
    const float* bv = (const float*)d_in[8];
    float* out = (float*)d_out;

    char* ws = (char*)d_ws;
    const size_t MB = 1024 * 1024;
    ushort* Ahi  = (ushort*)(ws + 0 * MB);
    ushort* Alo  = (ushort*)(ws + 8 * MB);
    ushort* WThi = (ushort*)(ws + 16 * MB);   // 6 MB (3x1024x1024 bf16)
    int*    MZnz = (int*)   (ws + 22 * MB);   // 16 KB (4096 ints)
    int*    Flag = (int*)   (ws + 23 * MB);   // 4 B
    float*  cst  = (float*) (ws + 24 * MB);   // 1 MB (4096x64 fp32 cos/sin)
    ushort* Qhi  = (ushort*)(ws + 28 * MB);
    ushort* Qlo  = (ushort*)(ws + 36 * MB);
    ushort* Khi  = (ushort*)(ws + 44 * MB);
    ushort* VT   = (ushort*)(ws + 60 * MB);   // 8 MB
    ushort* Mbf  = (ushort*)(ws + 68 * MB);   // 8 MB (2048x2048 bf16)

    prep<<<dim3(9472), 256, 0, stream>>>(data, Ahi, Alo, mask, Mbf, MZnz,
                                         Wq, Wk, Wv, WThi, temporal, cst);
    gemm_qkv<<<dim3(768), 512, 0, stream>>>(
        Ahi, Alo, WThi, bq, bk, bv, cst, MZnz, Flag,
        Qhi, Qlo, Khi, VT);
    attn_mfma<<<dim3(BATCH * NHEAD * SEQ / 128), 256, 0, stream>>>(
        Qhi, Qlo, Khi, VT, Mbf, Flag, out);
}

// Round 16
// 233.129 us; speedup vs baseline: 1.1299x; 1.1299x over previous
//
#include <hip/hip_runtime.h>
#include <hip/hip_bf16.h>

#define D_MODEL 1024
#define NHEAD   16
#define HEAD_DIM 64
#define BATCH   2
#define SEQ     2048
#define NTOK    (BATCH*SEQ)   // 4096

// log2(10000)/64
#define FREQ_LOG2 0.20762050593046015f

typedef short  bfrag __attribute__((ext_vector_type(8)));  // 8 bf16 = 4 VGPR
typedef float  ffrag __attribute__((ext_vector_type(4)));  // C/D frag

__device__ inline ushort f2bf(float x) {
    __hip_bfloat16 h = __float2bfloat16(x);
    return __builtin_bit_cast(ushort, h);
}
__device__ inline void split_bf(float x, ushort& hi, ushort& lo) {
    __hip_bfloat16 h = __float2bfloat16(x);
    hi = __builtin_bit_cast(ushort, h);
    lo = f2bf(x - __bfloat162float(h));
}

// async global->LDS DMA, 16B per lane (lds dest = uniform base + lane*16)
__device__ inline void gload16(const ushort* g, ushort* l) {
    __builtin_amdgcn_global_load_lds(
        (const __attribute__((address_space(1))) void*)g,
        (__attribute__((address_space(3))) void*)l, 16, 0, 0);
}

// barrier that drains ONLY LDS ops (lgkmcnt) — leaves the wave-private
// global register prefetch loads (vmcnt) in flight across the barrier (T4).
__device__ inline void barrier_lds_only() {
    asm volatile("s_waitcnt lgkmcnt(0)\n\ts_barrier" ::: "memory");
}

// gemm prologue barrier: drain al(k=0) + stage(buf0), keep stage(buf1).
__device__ inline void barrier_vm4() {
    asm volatile("s_waitcnt vmcnt(4) lgkmcnt(0)\n\ts_barrier" ::: "memory");
}

// gemm steady-state barrier (T4 counted): per iter we issue 4 stage-DMAs
// (tile i+2) then 4 al-loads (tile i+1); keeping the 8 NEWEST in flight
// drains exactly stage(i+1) — the buffer the next iteration reads.
__device__ inline void barrier_vm8() {
    asm volatile("s_waitcnt vmcnt(8) lgkmcnt(0)\n\ts_barrier" ::: "memory");
}

// ---------------------------------------------------------------------------
// Fused pre-pass:
//   blocks [0,4096):     data -> Ahi/Alo bf16 hi/lo split
//   blocks [4096,8192):  mask nonzero flag MZnz (no bf16 conversion — attn's
//                        slow path reads fp32 mask directly; all-zero fast
//                        path reads nothing)
//   blocks [8192,8960):  W[k][n] -> WT[n][k] bf16 (LDS transpose)
//   blocks [8960,9472):  RoPE cos/sin table (fp32; bit-identical expressions)
// ---------------------------------------------------------------------------
__global__ __launch_bounds__(256)
void prep(const float* __restrict__ data, ushort* __restrict__ Ahi,
          ushort* __restrict__ Alo,
          const float* __restrict__ mask, int* __restrict__ MZnz,
          const float* __restrict__ Wq, const float* __restrict__ Wk,
          const float* __restrict__ Wv, ushort* __restrict__ WThi,
          const float* __restrict__ temporal, float* __restrict__ cst)
{
    __shared__ float T[64][65];
    __shared__ int bnz;
    const int bid = blockIdx.x, t = threadIdx.x;

    if (bid < 4096) {                       // split_data
        const int i4 = (bid * 256 + t) * 4;
        const float4 v = *(const float4*)(data + i4);
        ushort4 h, l;
        split_bf(v.x, h.x, l.x); split_bf(v.y, h.y, l.y);
        split_bf(v.z, h.z, l.z); split_bf(v.w, h.w, l.w);
        *(ushort4*)(Ahi + i4) = h;
        *(ushort4*)(Alo + i4) = l;
        return;
    }
    if (bid < 8192) {                       // mask nonzero flag
        const int mi = bid - 4096;
        const int i4 = (mi * 256 + t) * 4;
        const float4 v = *(const float4*)(mask + i4);
        const int nz = (v.x != 0.f) || (v.y != 0.f) || (v.z != 0.f) || (v.w != 0.f);
        if (t == 0) bnz = 0;
        __syncthreads();
        if (nz) atomicOr(&bnz, 1);
        __syncthreads();
        if (t == 0) MZnz[mi] = bnz;
        return;
    }
    if (bid < 8960) {                       // W transpose
        const int id  = bid - 8192;         // 0..767
        const int z   = id >> 8;
        const int rem = id & 255;
        const int k0  = (rem & 15) * 64, n0 = (rem >> 4) * 64;
        const float* W = (z == 0) ? Wq : (z == 1) ? Wk : Wv;
        ushort* thi = WThi + (size_t)z * D_MODEL * D_MODEL;

        #pragma unroll
        for (int i = 0; i < 4; i++) {
            const int f = i * 256 + t, r = f >> 4, c = (f & 15) * 4;
            const float4 v = *(const float4*)(W + (size_t)(k0 + r) * D_MODEL + n0 + c);
            T[r][c] = v.x; T[r][c + 1] = v.y; T[r][c + 2] = v.z; T[r][c + 3] = v.w;
        }
        __syncthreads();
        #pragma unroll
        for (int i = 0; i < 4; i++) {
            const int f = i * 256 + t, nr = f >> 4, kc = (f & 15) * 4;
            ushort4 h;
            h.x = f2bf(T[kc + 0][nr]);
            h.y = f2bf(T[kc + 1][nr]);
            h.z = f2bf(T[kc + 2][nr]);
            h.w = f2bf(T[kc + 3][nr]);
            const size_t o = (size_t)(n0 + nr) * D_MODEL + k0 + kc;
            *(ushort4*)(thi + o) = h;
        }
        return;
    }
    // RoPE table: cst[m*64 + d] = cos, [.. + d + 1] = sin  (d even)
    const int id3 = bid - 8960;             // 0..511
    const int m   = id3 * 8 + (t >> 5);     // 0..4095
    const int j   = t & 31;                 // pair index, d = 2j
    const float tv = temporal[m];
    const float fr = exp2f(-(float)(2 * j) * FREQ_LOG2);
    float s, c;
    __sincosf(tv * fr, &s, &c);
    *(float2*)(cst + (size_t)m * 64 + 2 * j) = make_float2(c, s);
}

// ---------------------------------------------------------------------------
// Kernel 3: bf16x2 GEMM 128x128xBK32 + bias + RoPE epilogue.  (R13 version —
// R14's 8-wave variant regressed: occupancy doubled but MFMA/barrier ratio
// halved; this 4-wave 128² structure at 624 TF is its measured ceiling.)
// Triple-buffered DMA staging (prefetch distance 2) + counted vmcnt(8)
// barrier.  Alo operand fed from registers.
// ---------------------------------------------------------------------------
#define BK 32   // K-step; one LDS row = 32 bf16 = 64B = 4 chunks of 16B

union GemmSM {
    ushort st[3][2][128 * BK];   // [buf][ahi,bhi][row*BK+col]  = 48 KB
    float  c[64 * 132];          // epilogue scratch (33.8 KB)
};

__global__ __launch_bounds__(256, 3)
void gemm_qkv(const ushort* __restrict__ Ahi, const ushort* __restrict__ Alo,
              const ushort* __restrict__ WThi,
              const float* __restrict__ bq, const float* __restrict__ bk,
              const float* __restrict__ bv, const float* __restrict__ cst,
              const int* __restrict__ MZnz, int* __restrict__ Flag,
              ushort* __restrict__ Qhi, ushort* __restrict__ Qlo,
              ushort* __restrict__ Khi,
              ushort* __restrict__ VT)
{
    __shared__ GemmSM sm;
    __shared__ int flg;
    // XCD swizzle: bidl%8 = XCD slot; XCD x gets m-slabs 4x..4x+3 for all n,z
    const int bidl = blockIdx.x;                 // 0..767
    const int xcd  = bidl & 7, kk = bidl >> 3;   // kk 0..95
    const int m0   = (xcd * 4 + (kk & 3)) * 128;
    const int nz   = kk >> 2;                    // 0..23
    const int n0   = (nz & 7) * 128;
    const int z    = nz >> 3;

    const int t = threadIdx.x;

    if (bidl == 0) {      // mask-zero flag reduce (16 KB read, one block)
        if (t == 0) flg = 0;
        __syncthreads();
        int acc = 0;
        const int4* z4 = (const int4*)MZnz;
        #pragma unroll
        for (int i = 0; i < 4; i++) {
            const int4 v = z4[t * 4 + i];
            acc |= v.x | v.y | v.z | v.w;
        }
        if (acc) atomicOr(&flg, 1);
        __syncthreads();
        if (t == 0) Flag[0] = flg;
    }

    const float* bias = (z == 0) ? bq : (z == 1) ? bk : bv;
    const ushort* Bh = WThi + (size_t)z * D_MODEL * D_MODEL;

    const int w = t >> 6, lane = t & 63;
    const int lane15 = lane & 15, quad8 = (lane >> 4) * 8, quad = lane >> 4;
    const int wm = (w >> 1) * 64, wn = (w & 1) * 64;

    ffrag acc[4][4];
    #pragma unroll
    for (int i = 0; i < 4; i++)
        #pragma unroll
        for (int j = 0; j < 4; j++) acc[i][j] = (ffrag){0.f, 0.f, 0.f, 0.f};

    // DMA staging (Ahi + B): lane i of a 16-row chunk covers row (i>>2);
    // fetches logical chunk (i&3)^((i>>3)&3) into physical chunk (i&3).
    const int wr = w * 32;                                  // wave's 32-row slab
    const int lr = lane >> 2;                               // row within chunk
    const int lc = (((lane & 3) ^ ((lane >> 3) & 3))) * 8;  // swizzled col (elems)

    auto stage = [&](int bsel, int k0) {
        #pragma unroll
        for (int ch = 0; ch < 2; ch++) {
            const int rb = wr + ch * 16;
            const ushort* ga = Ahi + (size_t)(m0 + rb + lr) * D_MODEL + k0 + lc;
            const ushort* gb = Bh  + (size_t)(n0 + rb + lr) * D_MODEL + k0 + lc;
            gload16(ga, &sm.st[bsel][0][rb * BK]);
            gload16(gb, &sm.st[bsel][1][rb * BK]);
        }
    };

    // Alo fragment prefetch (registers, direct from global) for k=0
    bfrag alp0, alp1, alp2, alp3;
    {
        alp0 = *(const bfrag*)(Alo + (size_t)(m0 + wm +  0 + lane15) * D_MODEL + quad8);
        alp1 = *(const bfrag*)(Alo + (size_t)(m0 + wm + 16 + lane15) * D_MODEL + quad8);
        alp2 = *(const bfrag*)(Alo + (size_t)(m0 + wm + 32 + lane15) * D_MODEL + quad8);
        alp3 = *(const bfrag*)(Alo + (size_t)(m0 + wm + 48 + lane15) * D_MODEL + quad8);
    }

    stage(0, 0);
    stage(1, BK);
    barrier_vm4();   // drain al(k=0)+stage(buf0); keep stage(buf1) in flight

    // read-side swizzle: logical chunk 'quad' at row (16-aligned + lane15)
    const int rdsw = (quad ^ ((lane15 >> 1) & 3)) * 8;

    int cur = 0;
    for (int i = 0; i < 32; i++) {
        const int k0 = i * BK;
        // 1) stage tile i+2 into buf (cur+2)%3 (tail: harmless over-read,
        //    buffer never consumed)
        const int st2 = (cur >= 1) ? cur - 1 : 2;
        stage(st2, k0 + 2 * BK);

        // 2) consume this tile's al regs; issue next tile's al prefetch
        //    (tail: over-read within mapped workspace, never consumed)
        bfrag al0 = alp0, al1 = alp1, al2 = alp2, al3 = alp3;
        {
            const int kn = k0 + BK;
            alp0 = *(const bfrag*)(Alo + (size_t)(m0 + wm +  0 + lane15) * D_MODEL + kn + quad8);
            alp1 = *(const bfrag*)(Alo + (size_t)(m0 + wm + 16 + lane15) * D_MODEL + kn + quad8);
            alp2 = *(const bfrag*)(Alo + (size_t)(m0 + wm + 32 + lane15) * D_MODEL + kn + quad8);
            alp3 = *(const bfrag*)(Alo + (size_t)(m0 + wm + 48 + lane15) * D_MODEL + kn + quad8);
        }

        bfrag ah[4];
        #pragma unroll
        for (int mt = 0; mt < 4; mt++)
            ah[mt] = *(const bfrag*)&sm.st[cur][0][(wm + mt * 16 + lane15) * BK + rdsw];

        #pragma unroll
        for (int nt = 0; nt < 4; nt++) {
            const bfrag bh = *(const bfrag*)&sm.st[cur][1][(wn + nt * 16 + lane15) * BK + rdsw];
            {
                ffrag a = acc[0][nt];
                a = __builtin_amdgcn_mfma_f32_16x16x32_bf16(ah[0], bh, a, 0, 0, 0);
                a = __builtin_amdgcn_mfma_f32_16x16x32_bf16(al0,   bh, a, 0, 0, 0);
                acc[0][nt] = a;
            }
            {
                ffrag a = acc[1][nt];
                a = __builtin_amdgcn_mfma_f32_16x16x32_bf16(ah[1], bh, a, 0, 0, 0);
                a = __builtin_amdgcn_mfma_f32_16x16x32_bf16(al1,   bh, a, 0, 0, 0);
                acc[1][nt] = a;
            }
            {
                ffrag a = acc[2][nt];
                a = __builtin_amdgcn_mfma_f32_16x16x32_bf16(ah[2], bh, a, 0, 0, 0);
                a = __builtin_amdgcn_mfma_f32_16x16x32_bf16(al2,   bh, a, 0, 0, 0);
                acc[2][nt] = a;
            }
            {
                ffrag a = acc[3][nt];
                a = __builtin_amdgcn_mfma_f32_16x16x32_bf16(ah[3], bh, a, 0, 0, 0);
                a = __builtin_amdgcn_mfma_f32_16x16x32_bf16(al3,   bh, a, 0, 0, 0);
                acc[3][nt] = a;
            }
        }
        // 3) counted barrier: drain stage(i+1); keep stage(i+2)+al(i+1)
        barrier_vm8();
        cur = (cur == 2) ? 0 : cur + 1;
    }

    float bn[4];
    #pragma unroll
    for (int nt = 0; nt < 4; nt++) bn[nt] = bias[n0 + wn + nt * 16 + lane15];

    const int CST = (z == 2) ? 129 : 132;

    #pragma unroll
    for (int p = 0; p < 2; p++) {
        if (p) __syncthreads();
        if ((w >> 1) == p) {
            #pragma unroll
            for (int mt = 0; mt < 4; mt++)
                #pragma unroll
                for (int nt = 0; nt < 4; nt++)
                    #pragma unroll
                    for (int rr = 0; rr < 4; rr++)
                        sm.c[(mt * 16 + quad * 4 + rr) * CST + wn + nt * 16 + lane15] =
                            acc[mt][nt][rr] + bn[nt];
        }
        __syncthreads();

        if (z < 2) {
            ushort* ohi = (z == 0) ? Qhi : Khi;
            const float sc = (z == 0) ? 0.125f : 1.0f;
            #pragma unroll
            for (int i = 0; i < 8; i++) {
                const int f = i * 256 + t, r = f >> 5, c4 = (f & 31) * 4;
                float4 v = *(float4*)&sm.c[r * 132 + c4];
                const int m = m0 + p * 64 + r;
                const float4 cs4 = *(const float4*)(cst + (size_t)m * 64 + (c4 & 63));
                const float c0 = cs4.x, s0 = cs4.y, c1v = cs4.z, s1 = cs4.w;
                const float y0 = (v.x * c0 - v.y * s0) * sc;
                const float y1 = (v.y * c0 + v.x * s0) * sc;
                const float y2 = (v.z * c1v - v.w * s1) * sc;
                const float y3 = (v.w * c1v + v.z * s1) * sc;
                ushort4 h, l;
                split_bf(y0, h.x, l.x); split_bf(y1, h.y, l.y);
                split_bf(y2, h.z, l.z); split_bf(y3, h.w, l.w);
                const size_t o = (size_t)m * D_MODEL + n0 + c4;
                *(ushort4*)(ohi + o) = h;
                if (z == 0) *(ushort4*)(Qlo + o) = l;   // K needs no lo
            }
        } else {
            const int bb = m0 >> 11;
            #pragma unroll
            for (int i = 0; i < 4; i++) {
                const int cid = i * 256 + t, col = cid >> 3, tg = (cid & 7) * 8;
                ushort u8[8];
                #pragma unroll
                for (int j = 0; j < 8; j++) u8[j] = f2bf(sm.c[(tg + j) * 129 + col]);
                const int ncol = n0 + col, hh = ncol >> 6, d = ncol & 63;
                const size_t dst = ((size_t)(bb * NHEAD + hh) * HEAD_DIM + d) * SEQ +
                                   (m0 & (SEQ - 1)) + p * 64 + tg;
                *(int4*)(VT + dst) = *(int4*)u8;
            }
        }
    }
}

// ---------------------------------------------------------------------------
// Kernel 4: MFMA flash attention — R13 structure (KVBLK=128 two-half tiles,
// dbuf K/V, single LDS-only barrier, XOR swizzles, setprio, mask-zero fast
// path, l via ones-MFMA, saddr-split prefetch).  R15: slow path reads the
// fp32 mask directly (Mbf buffer removed; more accurate, never hit in the
// all-zero-mask case anyway).
// ---------------------------------------------------------------------------
__global__ __launch_bounds__(256, 2)
void attn_mfma(const ushort* __restrict__ Qhi, const ushort* __restrict__ Qlo,
               const ushort* __restrict__ Khi,
               const ushort* __restrict__ VT,  const float* __restrict__ maskf,
               const int* __restrict__ Flag,
               float* __restrict__ out)
{
    __shared__ ushort lsK[2][128 * 64], lsV[2][64 * 128], lsP[128 * 64];

    const int bid  = blockIdx.x;
    const int bh   = (bid & 7) * 4 + (bid >> 7);
    const int qb   = (bid >> 3) & 15;
    const int b    = bh >> 4, h = bh & 15;
    const int q0   = qb * 128;

    const int t = threadIdx.x, w = t >> 6, lane = t & 63;
    const int lane15 = lane & 15, quad = lane >> 4;
    const size_t tok0 = (size_t)b * SEQ;

    const int mz = Flag[0];            // 0 => mask is entirely zero

    // loop-invariant Q fragments (A-layout), 2 subtiles per wave
    bfrag qh[2][2], ql[2][2];
    #pragma unroll
    for (int su = 0; su < 2; su++) {
        const size_t qrow = (tok0 + q0 + w * 32 + su * 16 + lane15) * D_MODEL +
                            h * HEAD_DIM;
        #pragma unroll
        for (int ks = 0; ks < 2; ks++) {
            qh[su][ks] = *(const bfrag*)(Qhi + qrow + ks * 32 + quad * 8);
            ql[su][ks] = *(const bfrag*)(Qlo + qrow + ks * 32 + quad * 8);
        }
    }

    // all-ones bf16 fragment (B-operand for the l-MFMA)
    const short one_bf = (short)0x3F80;
    const bfrag ones = {one_bf, one_bf, one_bf, one_bf,
                        one_bf, one_bf, one_bf, one_bf};

    ffrag of[2][4], of_l[2];
    #pragma unroll
    for (int su = 0; su < 2; su++) {
        of_l[su] = (ffrag){0.f, 0.f, 0.f, 0.f};
        #pragma unroll
        for (int nt = 0; nt < 4; nt++)
            of[su][nt] = (ffrag){0.f, 0.f, 0.f, 0.f};
    }

    // K staging: thread covers rows rK+{0,32,64,96}, 16B chunk at cK.
    const int rK  = t >> 3, cK = (t & 7) * 8;
    const int swK = ((t & 7) ^ (rK & 7)) * 8;          // 8-chunk XOR (row&7)
    // V staging: thread covers row rV (d), 4 chunks lch=(t&3)+4*ch of 16.
    const int rV   = t >> 2;
    const int keyV = ((rV & 3) << 2) | ((rV >> 2) & 3);
    const ushort* Kh0 = Khi + tok0 * D_MODEL + h * HEAD_DIM;
    const ushort* Vt0 = VT + (size_t)(b * NHEAD + h) * HEAD_DIM * SEQ;

    // loop-invariant per-lane offsets (saddr-split)
    const size_t kof0 = (size_t)(rK +  0) * D_MODEL + cK;
    const size_t kof1 = (size_t)(rK + 32) * D_MODEL + cK;
    const size_t kof2 = (size_t)(rK + 64) * D_MODEL + cK;
    const size_t kof3 = (size_t)(rK + 96) * D_MODEL + cK;
    const size_t vof  = (size_t)rV * SEQ + (t & 3) * 8;

    // tile 0 (k 0..127) into regs
    int4 pk0 = *(const int4*)(Kh0 + kof0);
    int4 pk1 = *(const int4*)(Kh0 + kof1);
    int4 pk2 = *(const int4*)(Kh0 + kof2);
    int4 pk3 = *(const int4*)(Kh0 + kof3);
    int4 pv0 = *(const int4*)(Vt0 + vof +  0);
    int4 pv1 = *(const int4*)(Vt0 + vof + 32);
    int4 pv2 = *(const int4*)(Vt0 + vof + 64);
    int4 pv3 = *(const int4*)(Vt0 + vof + 96);

    // tile 0 regs -> buf0
    *(int4*)&lsK[0][(rK +  0) * 64 + swK] = pk0;
    *(int4*)&lsK[0][(rK + 32) * 64 + swK] = pk1;
    *(int4*)&lsK[0][(rK + 64) * 64 + swK] = pk2;
    *(int4*)&lsK[0][(rK + 96) * 64 + swK] = pk3;
    *(int4*)&lsV[0][rV * 128 + (((t & 3) +  0) ^ keyV) * 8] = pv0;
    *(int4*)&lsV[0][rV * 128 + (((t & 3) +  4) ^ keyV) * 8] = pv1;
    *(int4*)&lsV[0][rV * 128 + (((t & 3) +  8) ^ keyV) * 8] = pv2;
    *(int4*)&lsV[0][rV * 128 + (((t & 3) + 12) ^ keyV) * 8] = pv3;

    // tile 1 (k 128..255) into regs
    pk0 = *(const int4*)(Kh0 + 128 * D_MODEL + kof0);
    pk1 = *(const int4*)(Kh0 + 128 * D_MODEL + kof1);
    pk2 = *(const int4*)(Kh0 + 128 * D_MODEL + kof2);
    pk3 = *(const int4*)(Kh0 + 128 * D_MODEL + kof3);
    pv0 = *(const int4*)(Vt0 + 128 + vof +  0);
    pv1 = *(const int4*)(Vt0 + 128 + vof + 32);
    pv2 = *(const int4*)(Vt0 + 128 + vof + 64);
    pv3 = *(const int4*)(Vt0 + 128 + vof + 96);
    barrier_lds_only();

    const float* mrow0 = maskf + (size_t)(q0 + w * 32 + quad * 4) * SEQ;
    const float* mrow1 = maskf + (size_t)(q0 + w * 32 + 16 + quad * 4) * SEQ;

    const int krd  = lane15 & 7;                                  // K rows
    const int keyr = (((lane15 >> 2) & 3) << 1) | (lane15 & 1);   // P rows
    const int keyVr = ((lane15 & 3) << 2) | ((lane15 >> 2) & 3);  // V rows

    int cur = 0;
    for (int kt = 0; kt < SEQ; kt += 128) {
        // 1) regs (tile kt+128) -> buf cur^1
        if (kt + 128 < SEQ) {
            *(int4*)&lsK[cur ^ 1][(rK +  0) * 64 + swK] = pk0;
            *(int4*)&lsK[cur ^ 1][(rK + 32) * 64 + swK] = pk1;
            *(int4*)&lsK[cur ^ 1][(rK + 64) * 64 + swK] = pk2;
            *(int4*)&lsK[cur ^ 1][(rK + 96) * 64 + swK] = pk3;
            *(int4*)&lsV[cur ^ 1][rV * 128 + (((t & 3) +  0) ^ keyV) * 8] = pv0;
            *(int4*)&lsV[cur ^ 1][rV * 128 + (((t & 3) +  4) ^ keyV) * 8] = pv1;
            *(int4*)&lsV[cur ^ 1][rV * 128 + (((t & 3) +  8) ^ keyV) * 8] = pv2;
            *(int4*)&lsV[cur ^ 1][rV * 128 + (((t & 3) + 12) ^ keyV) * 8] = pv3;
        }

        // 2) global prefetch tile kt+256 (wrap -> harmless reload of tile 0)
        const int ktn = (kt + 256 < SEQ) ? kt + 256 : 0;
        const ushort* KhT = Kh0 + (size_t)ktn * D_MODEL;   // wave-uniform base
        const ushort* VtT = Vt0 + ktn;
        pk0 = *(const int4*)(KhT + kof0);
        pk1 = *(const int4*)(KhT + kof1);
        pk2 = *(const int4*)(KhT + kof2);
        pk3 = *(const int4*)(KhT + kof3);
        pv0 = *(const int4*)(VtT + vof +  0);
        pv1 = *(const int4*)(VtT + vof + 32);
        pv2 = *(const int4*)(VtT + vof + 64);
        pv3 = *(const int4*)(VtT + vof + 96);

        // 3) two 64-halves; no barrier between (P reuse safe: DS in-order)
        #pragma unroll
        for (int half = 0; half < 2; half++) {
            const int kb = kt + half * 64;

            // mask (fp32) — only when mask has nonzeros
            float mv0[4][4], mv1[4][4];
            if (mz) {
                #pragma unroll
                for (int nt = 0; nt < 4; nt++)
                    #pragma unroll
                    for (int rr = 0; rr < 4; rr++) {
                        mv0[nt][rr] = mrow0[(size_t)rr * SEQ + kb + nt * 16 + lane15];
                        mv1[nt][rr] = mrow1[(size_t)rr * SEQ + kb + nt * 16 + lane15];
                    }
            }

            // S = (Q/8) K^T for both subtiles; kf read ONCE per nt
            ffrag s0[4], s1[4];
            __builtin_amdgcn_s_setprio(1);
            #pragma unroll
            for (int nt = 0; nt < 4; nt++) {
                const int krow = half * 64 + nt * 16 + lane15;
                const bfrag kf0 = *(const bfrag*)&lsK[cur][krow * 64 + ((0 + quad) ^ krd) * 8];
                const bfrag kf1 = *(const bfrag*)&lsK[cur][krow * 64 + ((4 + quad) ^ krd) * 8];
                ffrag a0 = (ffrag){0.f, 0.f, 0.f, 0.f};
                ffrag a1 = (ffrag){0.f, 0.f, 0.f, 0.f};
                a0 = __builtin_amdgcn_mfma_f32_16x16x32_bf16(qh[0][0], kf0, a0, 0, 0, 0);
                a0 = __builtin_amdgcn_mfma_f32_16x16x32_bf16(ql[0][0], kf0, a0, 0, 0, 0);
                a0 = __builtin_amdgcn_mfma_f32_16x16x32_bf16(qh[0][1], kf1, a0, 0, 0, 0);
                a0 = __builtin_amdgcn_mfma_f32_16x16x32_bf16(ql[0][1], kf1, a0, 0, 0, 0);
                a1 = __builtin_amdgcn_mfma_f32_16x16x32_bf16(qh[1][0], kf0, a1, 0, 0, 0);
                a1 = __builtin_amdgcn_mfma_f32_16x16x32_bf16(ql[1][0], kf0, a1, 0, 0, 0);
                a1 = __builtin_amdgcn_mfma_f32_16x16x32_bf16(qh[1][1], kf1, a1, 0, 0, 0);
                a1 = __builtin_amdgcn_mfma_f32_16x16x32_bf16(ql[1][1], kf1, a1, 0, 0, 0);
                s0[nt] = a0;
                s1[nt] = a1;
            }
            __builtin_amdgcn_s_setprio(0);

            // streaming softmax: exp, P^T -> swizzled LDS (l via ones-MFMA)
            #pragma unroll
            for (int nt = 0; nt < 4; nt++)
                #pragma unroll
                for (int rr = 0; rr < 4; rr++) {
                    const int pchk = (2 * nt + (lane15 >> 3)) ^ ((quad << 1) | (rr & 1));
                    float x0 = s0[nt][rr];
                    float x1 = s1[nt][rr];
                    if (mz) { x0 += mv0[nt][rr]; x1 += mv1[nt][rr]; }
                    const float e0 = __expf(x0);
                    lsP[(w * 32 + quad * 4 + rr) * 64 + pchk * 8 + (lane15 & 7)] = f2bf(e0);
                    const float e1 = __expf(x1);
                    lsP[(w * 32 + 16 + quad * 4 + rr) * 64 + pchk * 8 + (lane15 & 7)] = f2bf(e1);
                }

            // O += P V  and  l += P·ones  (P rows wave-private: no barrier)
            __builtin_amdgcn_s_setprio(1);
            #pragma unroll
            for (int ksl = 0; ksl < 2; ksl++) {
                const bfrag pf0 = *(const bfrag*)&lsP[(w * 32 + lane15) * 64 +
                                                      ((ksl * 4 + quad) ^ keyr) * 8];
                const bfrag pf1 = *(const bfrag*)&lsP[(w * 32 + 16 + lane15) * 64 +
                                                      ((ksl * 4 + quad) ^ keyr) * 8];
                const int lkc = half * 8 + ksl * 4 + quad;   // logical V k-chunk
                #pragma unroll
                for (int nt = 0; nt < 4; nt++) {
                    const bfrag vf = *(const bfrag*)&lsV[cur][(nt * 16 + lane15) * 128 +
                                                              (lkc ^ keyVr) * 8];
                    of[0][nt] = __builtin_amdgcn_mfma_f32_16x16x32_bf16(pf0, vf, of[0][nt], 0, 0, 0);
                    of[1][nt] = __builtin_amdgcn_mfma_f32_16x16x32_bf16(pf1, vf, of[1][nt], 0, 0, 0);
                }
                of_l[0] = __builtin_amdgcn_mfma_f32_16x16x32_bf16(pf0, ones, of_l[0], 0, 0, 0);
                of_l[1] = __builtin_amdgcn_mfma_f32_16x16x32_bf16(pf1, ones, of_l[1], 0, 0, 0);
            }
            __builtin_amdgcn_s_setprio(0);
        }

        // 4) single barrier per 128-tile — LDS-only drain (vmcnt counted)
        barrier_lds_only();
        cur ^= 1;
    }

    #pragma unroll
    for (int su = 0; su < 2; su++) {
        float inv[4];
        #pragma unroll
        for (int rr = 0; rr < 4; rr++)
            inv[rr] = 1.0f / of_l[su][rr];    // D columns all equal: full sum
        #pragma unroll
        for (int nt = 0; nt < 4; nt++)
            #pragma unroll
            for (int rr = 0; rr < 4; rr++)
                out[(tok0 + q0 + w * 32 + su * 16 + quad * 4 + rr) * D_MODEL +
                    h * HEAD_DIM + nt * 16 + lane15] = of[su][nt][rr] * inv[rr];
    }
}

// ---------------------------------------------------------------------------
extern "C" void kernel_launch(void* const* d_in, const int* in_sizes, int n_in,
                              void* d_out, int out_size, void* d_ws, size_t ws_size,
                              hipStream_t stream)
{
    const float* data     = (const float*)d_in[0];
    const float* temporal = (const float*)d_in[1];
    const float* mask     = (const float*)d_in[2];
    const float* Wq = (const float*)d_in[3];
    const float* bq = (const float*)d_in[4];
    const float* Wk = (const float*)d_in[5];
    const float* bk = (const float*)d_in[6];
    const float* Wv = (const float*)d_in[7];
    const float* bv = (const float*)d_in[8];
    float* out = (float*)d_out;

    char* ws = (char*)d_ws;
    const size_t MB = 1024 * 1024;
    ushort* Ahi  = (ushort*)(ws + 0 * MB);
    ushort* Alo  = (ushort*)(ws + 8 * MB);
    ushort* WThi = (ushort*)(ws + 16 * MB);   // 6 MB (3x1024x1024 bf16)
    int*    MZnz = (int*)   (ws + 22 * MB);   // 16 KB (4096 ints)
    int*    Flag = (int*)   (ws + 23 * MB);   // 4 B
    float*  cst  = (float*) (ws + 24 * MB);   // 1 MB (4096x64 fp32 cos/sin)
    ushort* Qhi  = (ushort*)(ws + 28 * MB);
    ushort* Qlo  = (ushort*)(ws + 36 * MB);
    ushort* Khi  = (ushort*)(ws + 44 * MB);
    ushort* VT   = (ushort*)(ws + 60 * MB);   // 8 MB

    prep<<<dim3(9472), 256, 0, stream>>>(data, Ahi, Alo, mask, MZnz,
                                         Wq, Wk, Wv, WThi, temporal, cst);
    gemm_qkv<<<dim3(768), 256, 0, stream>>>(
        Ahi, Alo, WThi, bq, bk, bv, cst, MZnz, Flag,
        Qhi, Qlo, Khi, VT);
    attn_mfma<<<dim3(BATCH * NHEAD * SEQ / 128), 256, 0, stream>>>(
        Qhi, Qlo, Khi, VT, mask, Flag, out);
}